// Round 7
// baseline (66.217 us; speedup 1.0000x reference)
//
#include <hip/hip_runtime.h>

#define EPS   1e-5f
#define NB    16
#define NS    2048
#define ND    768
#define NK    64
#define NPB   (NS * ND)      /* 1572864 elems per batch */

typedef __attribute__((ext_vector_type(8))) short short8;
typedef __attribute__((ext_vector_type(4))) float f32x4;

static __device__ __forceinline__ short f2bf(float f) {
    unsigned u = __builtin_bit_cast(unsigned, f);
    u += 0x7fffu + ((u >> 16) & 1u);   // round-to-nearest-even
    return (short)(u >> 16);
}

// ---------------------------------------------------------------------------
// Kernel 1: per-batch partial sums (NO atomics) + weight prep.  (unchanged)
// ---------------------------------------------------------------------------
__global__ __launch_bounds__(256) void prep_reduce(
    const float* __restrict__ x, const float* __restrict__ W_up,
    const float* __restrict__ W_down, const float* __restrict__ W_ln,
    const float* __restrict__ b_ln, float2* __restrict__ stats_p,
    float* __restrict__ c1, float* __restrict__ c2,
    short* __restrict__ wdp, short* __restrict__ wub)
{
    __shared__ float red[8];
    const int bid = blockIdx.x, tid = threadIdx.x;
    const int wid = tid >> 6, lane = tid & 63;

    if (bid < 1024) {
        const int b = bid >> 6;
        const int chunk = bid & 63;
        const f32x4* xv = (const f32x4*)(x + (size_t)b * NPB + (size_t)chunk * (NPB / 64));
        float s = 0.f, ss = 0.f;
        #pragma unroll 8
        for (int i = tid; i < NPB / 64 / 4; i += 256) {
            f32x4 v = xv[i];
            s  += v[0] + v[1] + v[2] + v[3];
            ss += v[0]*v[0] + v[1]*v[1] + v[2]*v[2] + v[3]*v[3];
        }
        #pragma unroll
        for (int off = 32; off > 0; off >>= 1) {
            s  += __shfl_down(s, off, 64);
            ss += __shfl_down(ss, off, 64);
        }
        if (lane == 0) stats_p[bid * 4 + wid] = make_float2(s, ss);
    } else if (bid < 1088) {
        const int k = bid - 1024;
        float pc1 = 0.f, pc2 = 0.f;
        #pragma unroll
        for (int d = tid; d < ND; d += 256) {
            float wl = W_ln[d], wd = W_down[k * ND + d], bl = b_ln[d];
            wdp[k * ND + d] = f2bf(wl * wd);
            pc1 += wl * wd;
            pc2 += bl * wd;
        }
        #pragma unroll
        for (int off = 32; off > 0; off >>= 1) {
            pc1 += __shfl_down(pc1, off, 64);
            pc2 += __shfl_down(pc2, off, 64);
        }
        if (lane == 0) { red[wid] = pc1; red[4 + wid] = pc2; }
        __syncthreads();
        if (tid == 0) c1[k] = red[0] + red[1] + red[2] + red[3];
        if (tid == 1) c2[k] = red[4] + red[5] + red[6] + red[7];
    } else {
        const int i = (bid - 1088) * 256 + tid;   // exactly covers 49152
        wub[i] = f2bf(W_up[i]);
    }
}

// ---------------------------------------------------------------------------
// Kernel 2: fused LN + down-proj + ReLU + up-proj + residual.
// R6 structure with ONE structural delta: x staged to LDS (bf16) for GEMM1
// using the proven 384B-row XOR-swizzle layout; A-frags via ds_read_b128.
// LDS map (74752 B, 2 blocks/CU):
//  [0,49152)     GEMM1: wdp chunk [0,24576) + x chunk [24576,49152)
//                GEMM2: wub dbuf 2x16384
//  [49152,66560) stg: 4 waves x 16x68 f32 transpose buffer (proven)
//  [66560,74752) h:   4 waves x 2048B (proven)
// ---------------------------------------------------------------------------
__global__ __launch_bounds__(256) void fused_main(
    const float* __restrict__ x, const short* __restrict__ wdp,
    const short* __restrict__ wub, const float* __restrict__ c1,
    const float* __restrict__ c2, const float2* __restrict__ stats_p,
    float* __restrict__ out)
{
    __shared__ __align__(16) char lds[74752];

    const int tid  = threadIdx.x;
    const int wid  = tid >> 6;
    const int lane = tid & 63;
    const int r    = lane & 15;        // MFMA row (A) / col (B,D)
    const int g    = lane >> 4;        // k-group
    const int sw   = (r & 7) << 4;     // read-side XOR swizzle
    const int row0 = blockIdx.x * 64;  // block's first row
    const int b    = blockIdx.x >> 5;  // 32 blocks per batch

    // ---- fold the 256 per-wave partials for this batch (L2-hit) ----------
    float s = 0.f, ss = 0.f;
    #pragma unroll
    for (int i = 0; i < 4; ++i) {
        float2 sp = stats_p[b * 256 + i * 64 + lane];
        s += sp.x; ss += sp.y;
    }
    #pragma unroll
    for (int off = 32; off > 0; off >>= 1) {
        s  += __shfl_xor(s, off, 64);
        ss += __shfl_xor(ss, off, 64);
    }
    const float invN = 1.f / (float)NPB;
    const float mu  = s * invN;
    const float var = ss * invN - mu * mu;
    const float rs  = rsqrtf(var + EPS);

    // ---- staging helpers (proven 384B/128B-row XOR-swizzled layouts) ------
    auto stage_wdp = [&](int c) {          // wdp[:, c*192..+192) -> 64 rows x 384B
        char* dst = lds;
        #pragma unroll
        for (int i = 0; i < 6; ++i) {
            int idx = i * 256 + tid;               // 16B units, [0,1536)
            int row = idx / 24, u = idx % 24;
            short8 v = *(const short8*)(wdp + row * ND + c * 192 + u * 8);
            *(short8*)(dst + row * 384 + ((u * 16) ^ ((row & 7) << 4))) = v;
        }
    };
    auto stage_x = [&](int c) {            // x[row0..+64, c*192..+192) -> bf16, 64 rows x 384B
        char* dst = lds + 24576;
        #pragma unroll
        for (int i = 0; i < 6; ++i) {
            int idx = i * 256 + tid;               // 16B(bf16) units, [0,1536)
            int row = idx / 24, u = idx % 24;
            const float* src = x + (size_t)(row0 + row) * ND + c * 192 + u * 8;
            f32x4 a0 = *(const f32x4*)(src);
            f32x4 a1 = *(const f32x4*)(src + 4);
            short8 h8;
            h8[0]=f2bf(a0[0]); h8[1]=f2bf(a0[1]); h8[2]=f2bf(a0[2]); h8[3]=f2bf(a0[3]);
            h8[4]=f2bf(a1[0]); h8[5]=f2bf(a1[1]); h8[6]=f2bf(a1[2]); h8[7]=f2bf(a1[3]);
            *(short8*)(dst + row * 384 + ((u * 16) ^ ((row & 7) << 4))) = h8;
        }
    };
    auto stage_wub = [&](int w, int p) {   // wub rows [w*128,+128) -> 128 rows x 128B
        char* dst = lds + p * 16384;
        #pragma unroll
        for (int i = 0; i < 4; ++i) {
            int idx = i * 256 + tid;               // 16B units, [0,1024)
            int row = idx >> 3, u = idx & 7;
            short8 v = *(const short8*)(wub + (w * 128 + row) * 64 + u * 8);
            *(short8*)(dst + row * 128 + ((u * 16) ^ ((row & 7) << 4))) = v;
        }
    };

    // ---- GEMM1: 4 chunks of 192 d-cols; A and B both from swizzled LDS ----
    f32x4 acc[4] = {};
    for (int c = 0; c < 4; ++c) {
        stage_wdp(c);
        stage_x(c);
        __syncthreads();
        {
            const char* B = lds;
            const char* X = lds + 24576;
            const int arow = wid * 16 + r;
            #pragma unroll
            for (int kk = 0; kk < 6; ++kk) {
                short8 af = *(const short8*)(X + arow * 384 + ((kk * 64 + g * 16) ^ sw));
                #pragma unroll
                for (int cf = 0; cf < 4; ++cf) {
                    short8 bf = *(const short8*)(B + (cf * 16 + r) * 384
                                                   + ((kk * 64 + g * 16) ^ sw));
                    acc[cf] = __builtin_amdgcn_mfma_f32_16x16x32_bf16(af, bf, acc[cf], 0, 0, 0);
                }
            }
        }
        __syncthreads();
    }

    // ---- stage first wub chunk + epilogue 1 (z -> relu -> h, bf16) --------
    stage_wub(0, 0);
    char* H = lds + 66560 + wid * 2048;
    #pragma unroll
    for (int cf = 0; cf < 4; ++cf) {
        const int col = cf * 16 + r;
        const float kb = c2[col] - rs * mu * c1[col];
        #pragma unroll
        for (int reg = 0; reg < 4; ++reg) {
            float z = fmaf(rs, acc[cf][reg], kb);
            const int hrow = g * 4 + reg;
            *(short*)(H + hrow * 128 + ((col * 2) ^ ((hrow & 7) << 4))) = f2bf(fmaxf(z, 0.f));
        }
    }
    __syncthreads();

    // ---- GEMM2 A-fragments (own wave's h, K=64) ---------------------------
    short8 a2_0 = *(const short8*)(H + r * 128 + ((g * 16) ^ sw));
    short8 a2_1 = *(const short8*)(H + r * 128 + ((64 + g * 16) ^ sw));

    const float* xr   = x   + (size_t)(row0 + wid * 16) * ND;
    float*       outr = out + (size_t)(row0 + wid * 16) * ND;
    const int erow = lane >> 4;        // 0..3   (full-line epilogue mapping)
    const int ecol = (lane & 15) * 4;  // 0..60
    float* S = (float*)(lds + 49152) + wid * 1088;   // 16x68 f32 (proven)

    for (int w = 0; w < 6; ++w) {
        if (w < 5) stage_wub(w + 1, (w + 1) & 1);
        const char* W = lds + (w & 1) * 16384;
        #pragma unroll
        for (int dq = 0; dq < 2; ++dq) {
            const int dcg = w * 2 + dq;                    // global 64-col chunk
            f32x4 acc2[4] = {};
            #pragma unroll
            for (int cf = 0; cf < 4; ++cf) {
                const int dl = dq * 64 + cf * 16 + r;      // local wub row
                short8 b0 = *(const short8*)(W + dl * 128 + ((g * 16) ^ sw));
                short8 b1 = *(const short8*)(W + dl * 128 + ((64 + g * 16) ^ sw));
                acc2[cf] = __builtin_amdgcn_mfma_f32_16x16x32_bf16(a2_0, b0, acc2[cf], 0, 0, 0);
                acc2[cf] = __builtin_amdgcn_mfma_f32_16x16x32_bf16(a2_1, b1, acc2[cf], 0, 0, 0);
            }
            // transpose C/D layout -> row-major via per-wave LDS (stride 68)
            #pragma unroll
            for (int cf = 0; cf < 4; ++cf)
                #pragma unroll
                for (int reg = 0; reg < 4; ++reg)
                    S[(g * 4 + reg) * 68 + cf * 16 + r] = acc2[cf][reg];
            // full-line residual add + single f32x4 nt store per j
            #pragma unroll
            for (int j = 0; j < 4; ++j) {
                const int row = j * 4 + erow;
                f32x4 v  = *(const f32x4*)(S + row * 68 + ecol);
                const int col = dcg * 64 + ecol;
                f32x4 xv = *(const f32x4*)(xr + (size_t)row * ND + col);
                v[0] += xv[0]; v[1] += xv[1]; v[2] += xv[2]; v[3] += xv[3];
                __builtin_nontemporal_store(v, (f32x4*)(outr + (size_t)row * ND + col));
            }
        }
        __syncthreads();
    }
}

// ---------------------------------------------------------------------------
extern "C" void kernel_launch(void* const* d_in, const int* in_sizes, int n_in,
                              void* d_out, int out_size, void* d_ws, size_t ws_size,
                              hipStream_t stream)
{
    const float* x      = (const float*)d_in[0];
    const float* W_up   = (const float*)d_in[1];
    // d_in[2] = b_up   (unused by reference)
    const float* W_down = (const float*)d_in[3];
    // d_in[4] = b_down (unused by reference)
    const float* W_ln   = (const float*)d_in[5];
    const float* b_ln   = (const float*)d_in[6];
    float* out = (float*)d_out;

    char* ws = (char*)d_ws;
    float2* stats_p = (float2*)ws;                 // 4096 x float2 = 32 KiB
    float*  c1      = (float*)(ws + 32768);        // 64 f32
    float*  c2      = (float*)(ws + 33024);        // 64 f32
    short*  wdp     = (short*)(ws + 33280);        // bf16 [64][768] = 96 KiB
    short*  wub     = (short*)(ws + 131584);       // bf16 [768][64] = 96 KiB

    prep_reduce<<<1280, 256, 0, stream>>>(x, W_up, W_down, W_ln, b_ln,
                                          stats_p, c1, c2, wdp, wub);
    fused_main<<<512, 256, 0, stream>>>(x, wdp, wub, c1, c2, stats_p, out);
}